// Round 13
// baseline (94.416 us; speedup 1.0000x reference)
//
#include <hip/hip_runtime.h>
#include <cfloat>
#include <cstdint>

#define NSEG 512
#define C 21
#define PPB 512                   // points per chunk
#define EPS_PICK 1e-3f            // >= 2*deltaM (MFMA emu) and >= deltaM+delta32 (filter)

typedef short short8 __attribute__((ext_vector_type(8)));     // 8 bf16 (MFMA A/B frag)
typedef float f32x4 __attribute__((ext_vector_type(4)));      // MFMA acc

// truncate r to bf16 (exact split: hi takes the top bits, r -= hi exact in f32)
__device__ inline unsigned short bsplit(float& r) {
    unsigned int u = __float_as_uint(r) & 0xFFFF0000u;
    r -= __uint_as_float(u);
    return (unsigned short)(u >> 16);
}

// ===================== K1: prep + scatter =====================
// bid 0..127 : point i=bid*256+t -> pts4 + ptsplit (A-side bf16 slots, frag-major)
// bid 0..63  : ALSO query q=bid*256+t -> qsplit (B-side slots, frag-major)
// bid 128..191: scatter chunk sb=bid-128 — self-contained stable counting sort of
//              d_points (out positions + sorted_orig); sb==0 also writes segbase[].
// K-slot layout (K=32, 21 used), per coord c (a=-2*p_c, b=q_c):
//   slots 6c..6c+5: A=[ah,ah,al,al,ah,a2]  B=[bh,bl,bh,bl,b2,bh]
//   slots 18..20:   A=|p|^2 hi/lo/lo2  B=[1,1,1];  slots 21..31: 0
__global__ __launch_bounds__(256)
void prep_scatter(const float* __restrict__ pts, const float* __restrict__ dpts,
                  const int* __restrict__ sptids,
                  float4* __restrict__ pts4, short8* __restrict__ ptsplit,
                  short8* __restrict__ qsplit, int* __restrict__ segbase,
                  int* __restrict__ sorted_orig, float* __restrict__ out,
                  int n, int m)
{
    __shared__ int slds[NSEG * 2 + 512];
    const int bid = blockIdx.x, t = threadIdx.x;

    if (bid >= 128) {
        // ---- scatter chunk sb: stable counting sort, 256 threads (R12-validated) ----
        int sb = bid - 128;
        int* Hb   = slds;                         // [512] counts with idx < sb*256
        int* Ht   = Hb + NSEG;                    // [512] total counts
        int* pair = Ht + NSEG;                    // [256] pair sums for scan
        int* segs = pair + 256;                   // [256] this chunk's sptids
        Hb[t] = 0; Hb[t + 256] = 0; Ht[t] = 0; Ht[t + 256] = 0;
        __syncthreads();
        int before = sb * 256;
        for (int idx = t; idx < m; idx += 256) {  // integer LDS atomics -> deterministic
            int s = sptids[idx];
            atomicAdd(&Ht[s], 1);
            if (idx < before) atomicAdd(&Hb[s], 1);
        }
        __syncthreads();
        int e0 = Ht[2 * t], e1 = Ht[2 * t + 1];
        int v = e0 + e1;
        pair[t] = v;
        __syncthreads();
        for (int off = 1; off < 256; off <<= 1) { // inclusive scan of pair sums
            int add = (t >= off) ? pair[t - off] : 0;
            __syncthreads();
            v += add; pair[t] = v;
            __syncthreads();
        }
        int prev = (t > 0) ? pair[t - 1] : 0;
        int b0 = prev;                            // exclusive base of bin 2t
        int b1 = prev + e0;                       // exclusive base of bin 2t+1
        if (sb == 0) { segbase[2 * t] = b0; segbase[2 * t + 1] = b1; }
        int hb0 = Hb[2 * t], hb1 = Hb[2 * t + 1];
        __syncthreads();                          // all Hb reads done before overwrite
        Hb[2 * t] = b0 + hb0;                     // write base for THIS chunk
        Hb[2 * t + 1] = b1 + hb1;
        int i = sb * 256 + t;
        segs[t] = (i < m) ? sptids[i] : -1;
        __syncthreads();
        if (i < m) {
            int seg = segs[t];
            int rank = 0;
            for (int j = 0; j < t; j++) rank += (segs[j] == seg) ? 1 : 0;  // stable
            int pos = Hb[seg] + rank;
            out[pos * 3 + 0] = dpts[i * 3 + 0];
            out[pos * 3 + 1] = dpts[i * 3 + 1];
            out[pos * 3 + 2] = dpts[i * 3 + 2];
            sorted_orig[pos] = i;
        }
        return;
    }

    // ---- point split (R7-validated) ----
    int i = bid * 256 + t;
    if (i < n) {
        float x = pts[i * 3 + 0], y = pts[i * 3 + 1], z = pts[i * 3 + 2];
        pts4[i] = make_float4(x, y, z, fmaf(x, x, fmaf(y, y, z * z)));
        unsigned short sl[24];
#pragma unroll
        for (int c = 0; c < 3; c++) {
            float a = -2.f * ((c == 0) ? x : (c == 1) ? y : z);   // exact in f32
            float r = a;
            unsigned short ah = bsplit(r), al = bsplit(r), a2 = bsplit(r);
            sl[c * 6 + 0] = ah; sl[c * 6 + 1] = ah; sl[c * 6 + 2] = al;
            sl[c * 6 + 3] = al; sl[c * 6 + 4] = ah; sl[c * 6 + 5] = a2;
        }
        double pr = (double)x * x + (double)y * y + (double)z * z;
#pragma unroll
        for (int l = 0; l < 3; l++) {                             // |p|^2 hi/lo/lo2
            float f = (float)pr;
            unsigned int u = __float_as_uint(f) & 0xFFFF0000u;
            pr -= (double)__uint_as_float(u);
            sl[18 + l] = (unsigned short)(u >> 16);
        }
        sl[21] = 0; sl[22] = 0; sl[23] = 0;
        size_t base = (size_t)(i >> 4) * 64 + (i & 15);           // frag-major
        short8 g0, g1, g2, gz;
#pragma unroll
        for (int j = 0; j < 8; j++) { g0[j] = (short)sl[j]; g1[j] = (short)sl[8 + j]; g2[j] = (short)sl[16 + j]; gz[j] = 0; }
        ptsplit[base + 0] = g0; ptsplit[base + 16] = g1;
        ptsplit[base + 32] = g2; ptsplit[base + 48] = gz;
    }

    if (bid < 64) {                               // ---- query split (R7-validated) ----
        int q = bid * 256 + t;
        if (q < m) {
            unsigned short sl[24];
#pragma unroll
            for (int c = 0; c < 3; c++) {
                float b = dpts[q * 3 + c];
                float r = b;
                unsigned short bh = bsplit(r), bl = bsplit(r), b2 = bsplit(r);
                sl[c * 6 + 0] = bh; sl[c * 6 + 1] = bl; sl[c * 6 + 2] = bh;
                sl[c * 6 + 3] = bl; sl[c * 6 + 4] = b2; sl[c * 6 + 5] = bh;
            }
            sl[18] = 0x3F80; sl[19] = 0x3F80; sl[20] = 0x3F80;    // bf16 1.0
            sl[21] = 0; sl[22] = 0; sl[23] = 0;
            size_t base = (size_t)(q >> 4) * 64 + (q & 15);
            short8 g0, g1, g2, gz;
#pragma unroll
            for (int j = 0; j < 8; j++) { g0[j] = (short)sl[j]; g1[j] = (short)sl[8 + j]; g2[j] = (short)sl[16 + j]; gz[j] = 0; }
            qsplit[base + 0] = g0; qsplit[base + 16] = g1;
            qsplit[base + 32] = g2; qsplit[base + 48] = gz;
        }
    }
}

// ===================== K2: nn_mfma (R7-validated, verbatim) =====================
// Block = 8 waves x 128 queries = 1024 queries, 4 chunks of 512 points.
// Copy-staging: chunk loaded as float4 with next-chunk prefetch; MFMA on matrix pipe;
// per-chunk min -> pbvT[q][pc] (transposed for coalesced pick reads).
__global__ __launch_bounds__(512)
void nn_mfma(const short8* __restrict__ ptsplit, const short8* __restrict__ qsplit,
             float* __restrict__ pbvT, int m) {
    __shared__ short8 abuf[2048];                 // 32 KB: one 512-pt chunk, frag-major
    int t = threadIdx.x;
    int wave = t >> 6, lane = t & 63;
    int qb = blockIdx.x;                          // 16 blocks of 1024 queries
    int cg = blockIdx.y;                          // 16 groups of 4 chunks

    short8 bq[8];
    int qtbase = qb * 64 + wave * 8;
#pragma unroll
    for (int f = 0; f < 8; f++) bq[f] = qsplit[(size_t)(qtbase + f) * 64 + lane];

    const float4* psrc = (const float4*)ptsplit;
    float4* lbuf = (float4*)abuf;
    int c0 = cg * 4;
    float4 st0, st1, st2, st3;
    st0 = psrc[(size_t)c0 * 2048 + 0 * 512 + t];
    st1 = psrc[(size_t)c0 * 2048 + 1 * 512 + t];
    st2 = psrc[(size_t)c0 * 2048 + 2 * 512 + t];
    st3 = psrc[(size_t)c0 * 2048 + 3 * 512 + t];
    lbuf[0 * 512 + t] = st0; lbuf[1 * 512 + t] = st1;
    lbuf[2 * 512 + t] = st2; lbuf[3 * 512 + t] = st3;
    __syncthreads();

    for (int cl = 0; cl < 4; cl++) {
        int pc = c0 + cl;
        if (cl < 3) {                             // issue next-chunk loads early
            st0 = psrc[(size_t)(pc + 1) * 2048 + 0 * 512 + t];
            st1 = psrc[(size_t)(pc + 1) * 2048 + 1 * 512 + t];
            st2 = psrc[(size_t)(pc + 1) * 2048 + 2 * 512 + t];
            st3 = psrc[(size_t)(pc + 1) * 2048 + 3 * 512 + t];
        }
        float run[8];
#pragma unroll
        for (int f = 0; f < 8; f++) run[f] = FLT_MAX;
        f32x4 zero = {0.f, 0.f, 0.f, 0.f};
#pragma unroll 4
        for (int tt = 0; tt < 32; tt++) {
            short8 a = abuf[tt * 64 + lane];      // lane-contiguous b128: conflict-free
#pragma unroll
            for (int f = 0; f < 8; f++) {
                f32x4 acc = __builtin_amdgcn_mfma_f32_16x16x32_bf16(a, bq[f], zero, 0, 0, 0);
                float t1 = fminf(fminf(acc[0], acc[1]), acc[2]);          // v_min3
                run[f] = fminf(fminf(t1, acc[3]), run[f]);                // v_min3
            }
        }
#pragma unroll
        for (int f = 0; f < 8; f++) {             // merge 4 row-groups, write chunk min
            float v = run[f];
            v = fminf(v, __shfl_xor(v, 16, 64));
            v = fminf(v, __shfl_xor(v, 32, 64));
            if (lane < 16)
                pbvT[(size_t)(qb * 1024 + wave * 128 + f * 16 + lane) * 64 + pc] = v;
        }
        __syncthreads();
        if (cl < 3) {
            lbuf[0 * 512 + t] = st0; lbuf[1 * 512 + t] = st1;
            lbuf[2 * 512 + t] = st2; lbuf[3 * 512 + t] = st3;
            __syncthreads();
        }
    }
}

// ===================== K3: seg_pick_final (R12-validated, verbatim) =====================
// One block per segment (8 waves). Each wave resolves the NN for its members
// (j = base+wave, step 8): lane pc reads pbvT[q][pc], butterfly min -> g1,
// ballot(v<=g1+EPS) -> chunk mask, f32-filtered exact f64 resolve with
// lowest-index tie-break (== full f64 argmin). Lane c<21 accumulates
// scores[nn][c] in f64 in fixed (j, wave) order -> deterministic. Block reduce
// (fixed wave order) -> argmax (strict >, first max wins) -> labels written to
// original positions. argmax(sum) == argmax(mean).
__global__ __launch_bounds__(512)
void k2_seg_pick(const float4* __restrict__ pts4, const float* __restrict__ dpts,
                 const float* __restrict__ scores, const float* __restrict__ pbvT,
                 const int* __restrict__ segbase, const int* __restrict__ sorted_orig,
                 float* __restrict__ out, int n, int m)
{
    __shared__ double wsum[8][C];
    __shared__ double total[C];
    __shared__ float lab;
    const int t = threadIdx.x, wave = t >> 6, lane = t & 63;
    const int s = blockIdx.x;
    const int base = segbase[s];
    const int end  = (s == NSEG - 1) ? m : segbase[s + 1];

    double acc = 0.0;                             // channel `lane` partial (lanes 0..20)
    for (int j = base + wave; j < end; j += 8) {
        int q = sorted_orig[j];
        float myv = pbvT[(size_t)q * 64 + lane];  // chunk `lane` min (coalesced 256B)
        float g1 = myv;
#pragma unroll
        for (int off = 1; off < 64; off <<= 1) g1 = fminf(g1, __shfl_xor(g1, off, 64));
        float thr = g1 + EPS_PICK;
        unsigned long long msk = __ballot(myv <= thr);   // bit pc == chunk qualifies

        float fx = dpts[q * 3 + 0], fy = dpts[q * 3 + 1], fz = dpts[q * 3 + 2];
        float fm2x = -2.f * fx, fm2y = -2.f * fy, fm2z = -2.f * fz;
        double m2x = -2.0 * (double)fx, m2y = -2.0 * (double)fy, m2z = -2.0 * (double)fz;
        double best = 1e308; int bi = 0x7fffffff;
        while (msk) {
            int pc = __builtin_ctzll(msk); msk &= msk - 1;
            int pbase = pc * PPB + lane;
#pragma unroll
            for (int r2 = 0; r2 < PPB / 64; r2++) {
                int i = pbase + r2 * 64;
                if (i < n) {
                    float4 p = pts4[i];
                    float v = fmaf(p.x, fm2x, fmaf(p.y, fm2y, fmaf(p.z, fm2z, p.w)));
                    if (v <= thr) {
                        double ps = (double)p.x * p.x + (double)p.y * p.y + (double)p.z * p.z;
                        double dv = fma((double)p.x, m2x, fma((double)p.y, m2y,
                                    fma((double)p.z, m2z, ps)));
                        if (dv < best || (dv == best && i < bi)) { best = dv; bi = i; }
                    }
                }
            }
        }
#pragma unroll
        for (int off = 32; off; off >>= 1) {
            double ov = __shfl_down(best, off, 64);
            int oi = __shfl_down(bi, off, 64);
            if (ov < best || (ov == best && oi < bi)) { best = ov; bi = oi; }
        }
        int bi0 = __shfl(bi, 0, 64);              // broadcast winner index
        if (lane < C)
            acc += (double)scores[(size_t)bi0 * C + lane];
    }
    if (lane < C) wsum[wave][lane] = acc;         // all 8 waves write (0.0 if no members)
    __syncthreads();
    if (t < C) {
        double tv = 0.0;
#pragma unroll
        for (int w = 0; w < 8; w++) tv += wsum[w][t];   // fixed wave order
        total[t] = tv;
    }
    __syncthreads();
    if (t == 0) {
        double bv = total[0]; int best = 0;
        for (int c = 1; c < C; c++)
            if (total[c] > bv) { bv = total[c]; best = c; }  // strict >: first max wins
        lab = (float)best;
    }
    __syncthreads();
    float fb = lab;
    for (int j = base + t; j < end; j += 512)     // labels in ORIGINAL order
        out[(size_t)m * 3 + sorted_orig[j]] = fb;
}

extern "C" void kernel_launch(void* const* d_in, const int* in_sizes, int n_in,
                              void* d_out, int out_size, void* d_ws, size_t ws_size,
                              hipStream_t stream) {
    const float* points = (const float*)d_in[0];
    const float* scores = (const float*)d_in[1];
    const float* dpts   = (const float*)d_in[2];
    const int*   sptids = (const int*)d_in[3];

    int n = in_sizes[0] / 3;          // 32768
    int m = in_sizes[2] / 3;          // 16384
    int NPB = (n + 255) / 256;        // 128 point-prep blocks
    int NCH = (m + 255) / 256;        // 64 scatter chunks

    char* ws = (char*)d_ws;
    short8* ptsplit     = (short8*)ws;  ws += (size_t)n * 64;   // frag-major bf16 slots
    short8* qsplit      = (short8*)ws;  ws += (size_t)m * 64;
    float4* pts4        = (float4*)ws;  ws += (size_t)n * sizeof(float4);
    float*  pbvT        = (float*)ws;   ws += (size_t)m * 64 * sizeof(float);
    int*    segbase     = (int*)ws;     ws += (size_t)NSEG * sizeof(int);
    int*    sorted_orig = (int*)ws;     ws += (size_t)m * sizeof(int);

    prep_scatter<<<NPB + NCH, 256, 0, stream>>>(points, dpts, sptids,
                                                pts4, ptsplit, qsplit, segbase,
                                                sorted_orig, (float*)d_out, n, m);
    nn_mfma<<<dim3(16, 16), 512, 0, stream>>>(ptsplit, qsplit, pbvT, m);
    k2_seg_pick<<<NSEG, 512, 0, stream>>>(pts4, dpts, scores, pbvT,
                                          segbase, sorted_orig, (float*)d_out, n, m);
}

// Round 14
// 63.849 us; speedup vs baseline: 1.4787x; 1.4787x over previous
//
#include <hip/hip_runtime.h>
#include <cfloat>
#include <cstdint>

#define NSEG 512
#define C 21
#define PPB 512                   // points per chunk
#define EPS_PICK 1e-3f            // >= 2*deltaM (f16-split emu err ~2e-5) and >= deltaM+delta32

typedef _Float16 half8 __attribute__((ext_vector_type(8)));   // 8 f16 (MFMA A/B frag)
typedef float f32x16 __attribute__((ext_vector_type(16)));    // 32x32 MFMA acc

// ===================== K1: prep + scatter =====================
// bid 0..127 : point i -> pts4 + A-side f16 2-level split slots (frag-major)
// bid 0..63  : ALSO query q -> B-side slots (frag-major)
// bid 128..191: scatter chunk — stable counting sort of d_points (R12/R13-validated);
//              sb==0 also writes segbase[].
// K-slot layout (K=16, 11 used), per coord c (a=-2*p_c, b=q_c; ah/al = f16 Dekker split):
//   slots 3c..3c+2: A=[ah,ah,al]  B=[bh,bl,bh]      (drops al*bl ~2^-22 + residuals)
//   slots 9,10:     A=[s0,s1] (|p|^2 2-level f16)  B=[1,1];  slots 11..15: 0
__global__ __launch_bounds__(256)
void prep_scatter(const float* __restrict__ pts, const float* __restrict__ dpts,
                  const int* __restrict__ sptids,
                  float4* __restrict__ pts4, half8* __restrict__ pA,
                  half8* __restrict__ pB, int* __restrict__ segbase,
                  int* __restrict__ sorted_orig, float* __restrict__ out,
                  int n, int m)
{
    __shared__ int slds[NSEG * 2 + 512];
    const int bid = blockIdx.x, t = threadIdx.x;

    if (bid >= 128) {
        // ---- scatter chunk sb: stable counting sort, 256 threads ----
        int sb = bid - 128;
        int* Hb   = slds;                         // [512] counts with idx < sb*256
        int* Ht   = Hb + NSEG;                    // [512] total counts
        int* pair = Ht + NSEG;                    // [256] pair sums for scan
        int* segs = pair + 256;                   // [256] this chunk's sptids
        Hb[t] = 0; Hb[t + 256] = 0; Ht[t] = 0; Ht[t + 256] = 0;
        __syncthreads();
        int before = sb * 256;
        for (int idx = t; idx < m; idx += 256) {  // integer LDS atomics -> deterministic
            int s = sptids[idx];
            atomicAdd(&Ht[s], 1);
            if (idx < before) atomicAdd(&Hb[s], 1);
        }
        __syncthreads();
        int e0 = Ht[2 * t], e1 = Ht[2 * t + 1];
        int v = e0 + e1;
        pair[t] = v;
        __syncthreads();
        for (int off = 1; off < 256; off <<= 1) { // inclusive scan of pair sums
            int add = (t >= off) ? pair[t - off] : 0;
            __syncthreads();
            v += add; pair[t] = v;
            __syncthreads();
        }
        int prev = (t > 0) ? pair[t - 1] : 0;
        int b0 = prev, b1 = prev + e0;            // exclusive bases of bins 2t, 2t+1
        if (sb == 0) { segbase[2 * t] = b0; segbase[2 * t + 1] = b1; }
        int hb0 = Hb[2 * t], hb1 = Hb[2 * t + 1];
        __syncthreads();                          // all Hb reads done before overwrite
        Hb[2 * t] = b0 + hb0;
        Hb[2 * t + 1] = b1 + hb1;
        int i = sb * 256 + t;
        segs[t] = (i < m) ? sptids[i] : -1;
        __syncthreads();
        if (i < m) {
            int seg = segs[t];
            int rank = 0;
            for (int j = 0; j < t; j++) rank += (segs[j] == seg) ? 1 : 0;  // stable
            int pos = Hb[seg] + rank;
            out[pos * 3 + 0] = dpts[i * 3 + 0];
            out[pos * 3 + 1] = dpts[i * 3 + 1];
            out[pos * 3 + 2] = dpts[i * 3 + 2];
            sorted_orig[pos] = i;
        }
        return;
    }

    // ---- point split: A-side f16 slots ----
    int i = bid * 256 + t;
    if (i < n) {
        float x = pts[i * 3 + 0], y = pts[i * 3 + 1], z = pts[i * 3 + 2];
        pts4[i] = make_float4(x, y, z, fmaf(x, x, fmaf(y, y, z * z)));
        float a0 = -2.f * x, a1 = -2.f * y, a2 = -2.f * z;      // exact in f32
        _Float16 ah0 = (_Float16)a0; _Float16 al0 = (_Float16)(a0 - (float)ah0);
        _Float16 ah1 = (_Float16)a1; _Float16 al1 = (_Float16)(a1 - (float)ah1);
        _Float16 ah2 = (_Float16)a2; _Float16 al2 = (_Float16)(a2 - (float)ah2);
        double ps = (double)x * x + (double)y * y + (double)z * z;
        _Float16 s0 = (_Float16)(float)ps;
        double r1 = ps - (double)(float)s0;
        _Float16 s1 = (_Float16)(float)r1;
        half8 g0 = {ah0, ah0, al0, ah1, ah1, al1, ah2, ah2};    // slots 0..7
        half8 g1 = {al2, s0, s1, (_Float16)0.f, (_Float16)0.f,
                    (_Float16)0.f, (_Float16)0.f, (_Float16)0.f};  // slots 8..15
        // frag-major [tile(32pts)][row][k]: half8 idx = (i>>5)*64 + (i&31)*2 + g
        size_t base = (size_t)(i >> 5) * 64 + (size_t)(i & 31) * 2;
        pA[base + 0] = g0;
        pA[base + 1] = g1;
    }

    // ---- query split: B-side f16 slots ----
    if (bid < 64) {
        int q = bid * 256 + t;
        if (q < m) {
            float b0 = dpts[q * 3 + 0], b1 = dpts[q * 3 + 1], b2 = dpts[q * 3 + 2];
            _Float16 bh0 = (_Float16)b0; _Float16 bl0 = (_Float16)(b0 - (float)bh0);
            _Float16 bh1 = (_Float16)b1; _Float16 bl1 = (_Float16)(b1 - (float)bh1);
            _Float16 bh2 = (_Float16)b2; _Float16 bl2 = (_Float16)(b2 - (float)bh2);
            const _Float16 one = (_Float16)1.f, zz = (_Float16)0.f;
            half8 g0 = {bh0, bl0, bh0, bh1, bl1, bh1, bh2, bl2};   // slots 0..7
            half8 g1 = {bh2, one, one, zz, zz, zz, zz, zz};        // slots 8..15
            // frag-major per 32-query tile: entry idx = qt*64 + g*32 + col
            size_t qt = (size_t)(q >> 5), col = (size_t)(q & 31);
            pB[qt * 64 + 0 * 32 + col] = g0;
            pB[qt * 64 + 1 * 32 + col] = g1;
        }
    }
}

// ===================== K2: nn_mfma32 =====================
// Grid (qb=32, pc=64), 256 threads (4 waves). Stage chunk pc (512 pts x 32B = 16KB)
// via float4 memcpy; each wave: 4 query-tiles (128 queries) x 16 A-tiles, one
// 32x32x16 f16 MFMA each; fold 16 acc regs + xor(32) -> per-chunk min -> pbvT[q][pc].
// Min-reduction is invariant to A/C row permutations; relies only on D col=lane&31
// (HW-verified) and symmetric A/B k-grouping (lane>>5).
__global__ __launch_bounds__(256, 4)
void nn_mfma32(const half8* __restrict__ pA, const half8* __restrict__ pB,
               float* __restrict__ pbvT, int m)
{
    __shared__ half8 lbuf[1024];                  // 16 KB: one 512-pt chunk
    const int t = threadIdx.x;
    const int wave = t >> 6, lane = t & 63;
    const int qb = blockIdx.x, pc = blockIdx.y;

    half8 bq0, bq1, bq2, bq3;                     // 4 query tiles = 128 queries/wave
    {
        int qt = qb * 16 + wave * 4;
        bq0 = pB[(size_t)(qt + 0) * 64 + lane];
        bq1 = pB[(size_t)(qt + 1) * 64 + lane];
        bq2 = pB[(size_t)(qt + 2) * 64 + lane];
        bq3 = pB[(size_t)(qt + 3) * 64 + lane];
    }

    {   // stage chunk pc: 1024 float4 (16KB), 4 per thread
        const float4* src = (const float4*)(pA + (size_t)pc * 1024);
        float4* dst = (float4*)lbuf;
        dst[t]       = src[t];
        dst[t + 256] = src[t + 256];
        dst[t + 512] = src[t + 512];
        dst[t + 768] = src[t + 768];
    }
    __syncthreads();

    float run0 = FLT_MAX, run1 = FLT_MAX, run2 = FLT_MAX, run3 = FLT_MAX;
    const f32x16 zero = {0.f,0.f,0.f,0.f,0.f,0.f,0.f,0.f,0.f,0.f,0.f,0.f,0.f,0.f,0.f,0.f};
    const int aoff = (lane & 31) * 2 + (lane >> 5);

#pragma unroll 4
    for (int tt = 0; tt < 16; tt++) {
        half8 a = lbuf[tt * 64 + aoff];           // 16B b128, conflict-free
        f32x16 c0 = __builtin_amdgcn_mfma_f32_32x32x16_f16(a, bq0, zero, 0, 0, 0);
        f32x16 c1 = __builtin_amdgcn_mfma_f32_32x32x16_f16(a, bq1, zero, 0, 0, 0);
        f32x16 c2 = __builtin_amdgcn_mfma_f32_32x32x16_f16(a, bq2, zero, 0, 0, 0);
        f32x16 c3 = __builtin_amdgcn_mfma_f32_32x32x16_f16(a, bq3, zero, 0, 0, 0);
#define FOLD(cc, rr)  { \
        float v = fminf(fminf(cc[0], cc[1]), cc[2]);   \
        v = fminf(fminf(v, cc[3]), cc[4]);             \
        v = fminf(fminf(v, cc[5]), cc[6]);             \
        v = fminf(fminf(v, cc[7]), cc[8]);             \
        v = fminf(fminf(v, cc[9]), cc[10]);            \
        v = fminf(fminf(v, cc[11]), cc[12]);           \
        v = fminf(fminf(v, cc[13]), cc[14]);           \
        rr = fminf(fminf(v, cc[15]), rr); }
        FOLD(c0, run0) FOLD(c1, run1) FOLD(c2, run2) FOLD(c3, run3)
#undef FOLD
    }

    {   // merge the two 32-lane halves (rows), write 32 query chunk-mins per tile
        int qbase = (qb * 512 + wave * 128) * 64;
        float v0 = fminf(run0, __shfl_xor(run0, 32, 64));
        float v1 = fminf(run1, __shfl_xor(run1, 32, 64));
        float v2 = fminf(run2, __shfl_xor(run2, 32, 64));
        float v3 = fminf(run3, __shfl_xor(run3, 32, 64));
        if (lane < 32) {
            pbvT[(size_t)qbase + (0 * 32 + lane) * 64 + pc] = v0;
            pbvT[(size_t)qbase + (1 * 32 + lane) * 64 + pc] = v1;
            pbvT[(size_t)qbase + (2 * 32 + lane) * 64 + pc] = v2;
            pbvT[(size_t)qbase + (3 * 32 + lane) * 64 + pc] = v3;
        }
    }
}

// ===================== K3: pick (R11-validated, verbatim) =====================
// One wave per query: lane pc reads pbvT[q][pc] (coalesced 256B), butterfly min -> g1,
// ballot(v<=g1+EPS) -> qualifying-chunk mask; f32-filtered exact f64 resolve with
// lowest-index tie-break == full f64 argmin semantics (validated R1-R13).
__global__ __launch_bounds__(512)
void pick(const float4* __restrict__ pts4, const float* __restrict__ dpts,
          const float* __restrict__ pbvT, int* __restrict__ nn_idx, int n, int m)
{
    int wave = threadIdx.x >> 6, lane = threadIdx.x & 63;
    int q = blockIdx.x * 8 + wave;
    if (q >= m) return;

    float myv = pbvT[(size_t)q * 64 + lane];
    float g1 = myv;
#pragma unroll
    for (int off = 1; off < 64; off <<= 1) g1 = fminf(g1, __shfl_xor(g1, off, 64));
    float thr = g1 + EPS_PICK;
    unsigned long long msk = __ballot(myv <= thr);

    float fx = dpts[q * 3 + 0], fy = dpts[q * 3 + 1], fz = dpts[q * 3 + 2];
    float fm2x = -2.f * fx, fm2y = -2.f * fy, fm2z = -2.f * fz;
    double m2x = -2.0 * (double)fx, m2y = -2.0 * (double)fy, m2z = -2.0 * (double)fz;
    double best = 1e308; int bi = 0x7fffffff;
    while (msk) {
        int pc = __builtin_ctzll(msk); msk &= msk - 1;
        int base = pc * PPB + lane;
#pragma unroll
        for (int r2 = 0; r2 < PPB / 64; r2++) {
            int i = base + r2 * 64;
            if (i < n) {
                float4 p = pts4[i];
                float v = fmaf(p.x, fm2x, fmaf(p.y, fm2y, fmaf(p.z, fm2z, p.w)));
                if (v <= thr) {
                    double ps = (double)p.x * p.x + (double)p.y * p.y + (double)p.z * p.z;
                    double dv = fma((double)p.x, m2x, fma((double)p.y, m2y,
                                fma((double)p.z, m2z, ps)));
                    if (dv < best || (dv == best && i < bi)) { best = dv; bi = i; }
                }
            }
        }
    }
#pragma unroll
    for (int off = 32; off; off >>= 1) {
        double ov = __shfl_down(best, off, 64);
        int oi = __shfl_down(bi, off, 64);
        if (ov < best || (ov == best && oi < bi)) { best = ov; bi = oi; }
    }
    if (lane == 0) nn_idx[q] = bi;
}

// ===================== K4: seg_final (R11-validated, verbatim) =====================
__global__ __launch_bounds__(512)
void seg_final(const int* __restrict__ segbase, const int* __restrict__ sorted_orig,
               const int* __restrict__ nn_idx, const float* __restrict__ scores,
               float* __restrict__ out, int m)
{
    int wave = threadIdx.x >> 6, lane = threadIdx.x & 63;
    int s = blockIdx.x * 8 + wave;
    if (s >= NSEG) return;
    int base = segbase[s];
    int end  = (s == NSEG - 1) ? m : segbase[s + 1];
    double acc[C];
#pragma unroll
    for (int c = 0; c < C; c++) acc[c] = 0.0;
    for (int j = base + lane; j < end; j += 64) {
        const float* sp = scores + (size_t)nn_idx[sorted_orig[j]] * C;
#pragma unroll
        for (int c = 0; c < C; c++) acc[c] += (double)sp[c];
    }
#pragma unroll
    for (int c = 0; c < C; c++) {
        for (int off = 32; off; off >>= 1) acc[c] += __shfl_down(acc[c], off, 64);
    }
    int best = 0;
    if (lane == 0) {
        double bv = acc[0];
        for (int c = 1; c < C; c++)
            if (acc[c] > bv) { bv = acc[c]; best = c; }   // strict >: first max wins
    }
    best = __shfl(best, 0, 64);
    float fb = (float)best;
    for (int j = base + lane; j < end; j += 64)
        out[(size_t)m * 3 + sorted_orig[j]] = fb;
}

extern "C" void kernel_launch(void* const* d_in, const int* in_sizes, int n_in,
                              void* d_out, int out_size, void* d_ws, size_t ws_size,
                              hipStream_t stream) {
    const float* points = (const float*)d_in[0];
    const float* scores = (const float*)d_in[1];
    const float* dpts   = (const float*)d_in[2];
    const int*   sptids = (const int*)d_in[3];

    int n = in_sizes[0] / 3;          // 32768
    int m = in_sizes[2] / 3;          // 16384
    int NPB = (n + 255) / 256;        // 128 point-prep blocks
    int NCH = (m + 255) / 256;        // 64 scatter chunks
    int QB  = (m + 511) / 512;        // 32
    int PCg = (n + 511) / 512;        // 64

    char* ws = (char*)d_ws;
    half8*  pA          = (half8*)ws;   ws += (size_t)n * 32;   // A slots, frag-major
    half8*  pB          = (half8*)ws;   ws += (size_t)m * 32;   // B slots, frag-major
    float4* pts4        = (float4*)ws;  ws += (size_t)n * sizeof(float4);
    float*  pbvT        = (float*)ws;   ws += (size_t)m * 64 * sizeof(float);
    int*    nn_idx      = (int*)ws;     ws += (size_t)m * sizeof(int);
    int*    segbase     = (int*)ws;     ws += (size_t)NSEG * sizeof(int);
    int*    sorted_orig = (int*)ws;     ws += (size_t)m * sizeof(int);

    prep_scatter<<<NPB + NCH, 256, 0, stream>>>(points, dpts, sptids,
                                                pts4, pA, pB, segbase,
                                                sorted_orig, (float*)d_out, n, m);
    nn_mfma32<<<dim3(QB, PCg), 256, 0, stream>>>(pA, pB, pbvT, m);
    pick<<<(m + 7) / 8, 512, 0, stream>>>(pts4, dpts, pbvT, nn_idx, n, m);
    seg_final<<<NSEG / 8, 512, 0, stream>>>(segbase, sorted_orig, nn_idx, scores,
                                            (float*)d_out, m);
}

// Round 15
// 56.900 us; speedup vs baseline: 1.6593x; 1.1221x over previous
//
#include <hip/hip_runtime.h>
#include <cfloat>
#include <cstdint>

#define NSEG 512
#define C 21
#define PPB 512                   // points per chunk
#define EPS_PICK 1e-3f            // >= 2*deltaM (f16-split emu err ~2e-5) and >= deltaM+delta32

typedef _Float16 half8 __attribute__((ext_vector_type(8)));   // 8 f16 (MFMA A/B frag)
typedef float f32x16 __attribute__((ext_vector_type(16)));    // 32x32 MFMA acc

// ===================== K1: scatter + self-staged f16 MFMA =====================
// bid 0..63   : scatter chunk sb — self-contained stable counting sort of d_points
//               (out positions + sorted_orig); sb==0 also writes segbase[].
// bid 64..2111: mfma block b2=bid-64, qb=b2&31, pc=b2>>5 — self-stage chunk pc
//               (512 pts) as f16 2-level-split slots in LDS (frag-major, 16 KB) and
//               B-frags for 128 queries/wave from raw dpts; 16 tt x 4 MFMA
//               (32x32x16 f16); fold 16 accs + xor(32) -> per-chunk min pbvT[q][pc].
//               qb==0 blocks also write pts4. (MFMA body verbatim R14, validated)
// K-slot layout (K=16, 11 used), per coord c (a=-2*p_c, b=q_c; ah/al = f16 Dekker):
//   slots 3c..3c+2: A=[ah,ah,al]  B=[bh,bl,bh]
//   slots 9,10:     A=[s0,s1] (|p|^2 2-level)  B=[1,1];  slots 11..15: 0
__global__ __launch_bounds__(256, 4)
void k1_mfma_scatter(const float* __restrict__ pts, const float* __restrict__ dpts,
                     const int* __restrict__ sptids,
                     float4* __restrict__ pts4, float* __restrict__ pbvT,
                     int* __restrict__ segbase, int* __restrict__ sorted_orig,
                     float* __restrict__ out, int n, int m, int NCH)
{
    __shared__ half8 lbuf[1024];                  // 16 KB (A-chunk / scatter scratch)
    const int bid = blockIdx.x, t = threadIdx.x;

    if (bid < NCH) {
        // ---- scatter chunk sb: stable counting sort (R12-R14 validated) ----
        int sb = bid;
        int* Hb   = (int*)lbuf;                   // [512] counts with idx < sb*256
        int* Ht   = Hb + NSEG;                    // [512] total counts
        int* pair = Ht + NSEG;                    // [256] pair sums for scan
        int* segs = pair + 256;                   // [256] this chunk's sptids
        Hb[t] = 0; Hb[t + 256] = 0; Ht[t] = 0; Ht[t + 256] = 0;
        __syncthreads();
        int before = sb * 256;
        for (int idx = t; idx < m; idx += 256) {  // integer LDS atomics -> deterministic
            int s = sptids[idx];
            atomicAdd(&Ht[s], 1);
            if (idx < before) atomicAdd(&Hb[s], 1);
        }
        __syncthreads();
        int e0 = Ht[2 * t], e1 = Ht[2 * t + 1];
        int v = e0 + e1;
        pair[t] = v;
        __syncthreads();
        for (int off = 1; off < 256; off <<= 1) { // inclusive scan of pair sums
            int add = (t >= off) ? pair[t - off] : 0;
            __syncthreads();
            v += add; pair[t] = v;
            __syncthreads();
        }
        int prev = (t > 0) ? pair[t - 1] : 0;
        int b0 = prev, b1 = prev + e0;            // exclusive bases of bins 2t, 2t+1
        if (sb == 0) { segbase[2 * t] = b0; segbase[2 * t + 1] = b1; }
        int hb0 = Hb[2 * t], hb1 = Hb[2 * t + 1];
        __syncthreads();                          // all Hb reads done before overwrite
        Hb[2 * t] = b0 + hb0;
        Hb[2 * t + 1] = b1 + hb1;
        int i = sb * 256 + t;
        segs[t] = (i < m) ? sptids[i] : -1;
        __syncthreads();
        if (i < m) {
            int seg = segs[t];
            int rank = 0;
            for (int j = 0; j < t; j++) rank += (segs[j] == seg) ? 1 : 0;  // stable
            int pos = Hb[seg] + rank;
            out[pos * 3 + 0] = dpts[i * 3 + 0];
            out[pos * 3 + 1] = dpts[i * 3 + 1];
            out[pos * 3 + 2] = dpts[i * 3 + 2];
            sorted_orig[pos] = i;
        }
        return;
    }

    // ---- MFMA block ----
    const int b2 = bid - NCH;
    const int qb = b2 & 31, pc = b2 >> 5;
    const int wave = t >> 6, lane = t & 63;
    const int g = lane >> 5, col = lane & 31;

    // B-frags: 4 query-tiles/wave, each lane builds its (g, col) entry from raw dpts
    half8 bq[4];
#pragma unroll
    for (int k = 0; k < 4; k++) {
        int q = (qb * 16 + wave * 4 + k) * 32 + col;
        float b0 = dpts[q * 3 + 0], b1 = dpts[q * 3 + 1], b2c = dpts[q * 3 + 2];
        _Float16 bh0 = (_Float16)b0; _Float16 bl0 = (_Float16)(b0 - (float)bh0);
        _Float16 bh1 = (_Float16)b1; _Float16 bl1 = (_Float16)(b1 - (float)bh1);
        _Float16 bh2 = (_Float16)b2c; _Float16 bl2 = (_Float16)(b2c - (float)bh2);
        const _Float16 one = (_Float16)1.f, zz = (_Float16)0.f;
        half8 g0 = {bh0, bl0, bh0, bh1, bl1, bh1, bh2, bl2};   // slots 0..7
        half8 g1 = {bh2, one, one, zz, zz, zz, zz, zz};        // slots 8..15
        bq[k] = g ? g1 : g0;
    }

    // A-chunk self-stage: thread stages points j=t and j+256 of chunk pc
#pragma unroll
    for (int half = 0; half < 2; half++) {
        int j = half * 256 + t;
        int i = pc * PPB + j;
        float x = pts[i * 3 + 0], y = pts[i * 3 + 1], z = pts[i * 3 + 2];
        if (qb == 0)                              // pts4 written exactly once per point
            pts4[i] = make_float4(x, y, z, fmaf(x, x, fmaf(y, y, z * z)));
        float a0 = -2.f * x, a1 = -2.f * y, a2 = -2.f * z;      // exact in f32
        _Float16 ah0 = (_Float16)a0; _Float16 al0 = (_Float16)(a0 - (float)ah0);
        _Float16 ah1 = (_Float16)a1; _Float16 al1 = (_Float16)(a1 - (float)ah1);
        _Float16 ah2 = (_Float16)a2; _Float16 al2 = (_Float16)(a2 - (float)ah2);
        double ps = (double)x * x + (double)y * y + (double)z * z;
        _Float16 s0 = (_Float16)(float)ps;
        double r1 = ps - (double)(float)s0;
        _Float16 s1 = (_Float16)(float)r1;
        half8 g0 = {ah0, ah0, al0, ah1, ah1, al1, ah2, ah2};    // slots 0..7
        half8 g1 = {al2, s0, s1, (_Float16)0.f, (_Float16)0.f,
                    (_Float16)0.f, (_Float16)0.f, (_Float16)0.f};
        int base = (j >> 5) * 64 + (j & 31) * 2;
        lbuf[base + 0] = g0;
        lbuf[base + 1] = g1;
    }
    __syncthreads();

    // ---- MFMA loop (verbatim R14, validated) ----
    float run0 = FLT_MAX, run1 = FLT_MAX, run2 = FLT_MAX, run3 = FLT_MAX;
    const f32x16 zero = {0.f,0.f,0.f,0.f,0.f,0.f,0.f,0.f,0.f,0.f,0.f,0.f,0.f,0.f,0.f,0.f};
    const int aoff = col * 2 + g;

#pragma unroll 4
    for (int tt = 0; tt < 16; tt++) {
        half8 a = lbuf[tt * 64 + aoff];           // 16B b128, conflict-free
        f32x16 c0 = __builtin_amdgcn_mfma_f32_32x32x16_f16(a, bq[0], zero, 0, 0, 0);
        f32x16 c1 = __builtin_amdgcn_mfma_f32_32x32x16_f16(a, bq[1], zero, 0, 0, 0);
        f32x16 c2 = __builtin_amdgcn_mfma_f32_32x32x16_f16(a, bq[2], zero, 0, 0, 0);
        f32x16 c3 = __builtin_amdgcn_mfma_f32_32x32x16_f16(a, bq[3], zero, 0, 0, 0);
#define FOLD(cc, rr)  { \
        float v = fminf(fminf(cc[0], cc[1]), cc[2]);   \
        v = fminf(fminf(v, cc[3]), cc[4]);             \
        v = fminf(fminf(v, cc[5]), cc[6]);             \
        v = fminf(fminf(v, cc[7]), cc[8]);             \
        v = fminf(fminf(v, cc[9]), cc[10]);            \
        v = fminf(fminf(v, cc[11]), cc[12]);           \
        v = fminf(fminf(v, cc[13]), cc[14]);           \
        rr = fminf(fminf(v, cc[15]), rr); }
        FOLD(c0, run0) FOLD(c1, run1) FOLD(c2, run2) FOLD(c3, run3)
#undef FOLD
    }

    {   // merge the two 32-lane halves (rows), write 32 query chunk-mins per tile
        int qbase = (qb * 512 + wave * 128) * 64;
        float v0 = fminf(run0, __shfl_xor(run0, 32, 64));
        float v1 = fminf(run1, __shfl_xor(run1, 32, 64));
        float v2 = fminf(run2, __shfl_xor(run2, 32, 64));
        float v3 = fminf(run3, __shfl_xor(run3, 32, 64));
        if (lane < 32) {
            pbvT[(size_t)qbase + (0 * 32 + lane) * 64 + pc] = v0;
            pbvT[(size_t)qbase + (1 * 32 + lane) * 64 + pc] = v1;
            pbvT[(size_t)qbase + (2 * 32 + lane) * 64 + pc] = v2;
            pbvT[(size_t)qbase + (3 * 32 + lane) * 64 + pc] = v3;
        }
    }
}

// ===================== K2: seg_pick_final (R12/R13-validated, verbatim) =====================
// One block per segment (8 waves). Each wave resolves the NN for its members
// (j = base+wave, step 8): lane pc reads pbvT[q][pc], butterfly min -> g1,
// ballot(v<=g1+EPS) -> chunk mask, f32-filtered exact f64 resolve with
// lowest-index tie-break (== full f64 argmin). Lane c<21 accumulates
// scores[nn][c] in f64 in fixed (j, wave) order -> deterministic. Block reduce
// (fixed wave order) -> argmax (strict >, first max wins) -> labels written to
// original positions. argmax(sum) == argmax(mean).
__global__ __launch_bounds__(512)
void k2_seg_pick(const float4* __restrict__ pts4, const float* __restrict__ dpts,
                 const float* __restrict__ scores, const float* __restrict__ pbvT,
                 const int* __restrict__ segbase, const int* __restrict__ sorted_orig,
                 float* __restrict__ out, int n, int m)
{
    __shared__ double wsum[8][C];
    __shared__ double total[C];
    __shared__ float lab;
    const int t = threadIdx.x, wave = t >> 6, lane = t & 63;
    const int s = blockIdx.x;
    const int base = segbase[s];
    const int end  = (s == NSEG - 1) ? m : segbase[s + 1];

    double acc = 0.0;                             // channel `lane` partial (lanes 0..20)
    for (int j = base + wave; j < end; j += 8) {
        int q = sorted_orig[j];
        float myv = pbvT[(size_t)q * 64 + lane];  // chunk `lane` min (coalesced 256B)
        float g1 = myv;
#pragma unroll
        for (int off = 1; off < 64; off <<= 1) g1 = fminf(g1, __shfl_xor(g1, off, 64));
        float thr = g1 + EPS_PICK;
        unsigned long long msk = __ballot(myv <= thr);   // bit pc == chunk qualifies

        float fx = dpts[q * 3 + 0], fy = dpts[q * 3 + 1], fz = dpts[q * 3 + 2];
        float fm2x = -2.f * fx, fm2y = -2.f * fy, fm2z = -2.f * fz;
        double m2x = -2.0 * (double)fx, m2y = -2.0 * (double)fy, m2z = -2.0 * (double)fz;
        double best = 1e308; int bi = 0x7fffffff;
        while (msk) {
            int pc = __builtin_ctzll(msk); msk &= msk - 1;
            int pbase = pc * PPB + lane;
#pragma unroll
            for (int r2 = 0; r2 < PPB / 64; r2++) {
                int i = pbase + r2 * 64;
                if (i < n) {
                    float4 p = pts4[i];
                    float v = fmaf(p.x, fm2x, fmaf(p.y, fm2y, fmaf(p.z, fm2z, p.w)));
                    if (v <= thr) {
                        double ps = (double)p.x * p.x + (double)p.y * p.y + (double)p.z * p.z;
                        double dv = fma((double)p.x, m2x, fma((double)p.y, m2y,
                                    fma((double)p.z, m2z, ps)));
                        if (dv < best || (dv == best && i < bi)) { best = dv; bi = i; }
                    }
                }
            }
        }
#pragma unroll
        for (int off = 32; off; off >>= 1) {
            double ov = __shfl_down(best, off, 64);
            int oi = __shfl_down(bi, off, 64);
            if (ov < best || (ov == best && oi < bi)) { best = ov; bi = oi; }
        }
        int bi0 = __shfl(bi, 0, 64);              // broadcast winner index
        if (lane < C)
            acc += (double)scores[(size_t)bi0 * C + lane];
    }
    if (lane < C) wsum[wave][lane] = acc;         // all 8 waves write (0.0 if no members)
    __syncthreads();
    if (t < C) {
        double tv = 0.0;
#pragma unroll
        for (int w = 0; w < 8; w++) tv += wsum[w][t];   // fixed wave order
        total[t] = tv;
    }
    __syncthreads();
    if (t == 0) {
        double bv = total[0]; int best = 0;
        for (int c = 1; c < C; c++)
            if (total[c] > bv) { bv = total[c]; best = c; }  // strict >: first max wins
        lab = (float)best;
    }
    __syncthreads();
    float fb = lab;
    for (int j = base + t; j < end; j += 512)     // labels in ORIGINAL order
        out[(size_t)m * 3 + sorted_orig[j]] = fb;
}

extern "C" void kernel_launch(void* const* d_in, const int* in_sizes, int n_in,
                              void* d_out, int out_size, void* d_ws, size_t ws_size,
                              hipStream_t stream) {
    const float* points = (const float*)d_in[0];
    const float* scores = (const float*)d_in[1];
    const float* dpts   = (const float*)d_in[2];
    const int*   sptids = (const int*)d_in[3];

    int n = in_sizes[0] / 3;          // 32768
    int m = in_sizes[2] / 3;          // 16384
    int NCH   = (m + 255) / 256;      // 64 scatter chunks
    int QB    = (m + 511) / 512;      // 32 query blocks
    int PCg   = (n + 511) / 512;      // 64 point chunks
    int MFMAB = QB * PCg;             // 2048 mfma blocks

    char* ws = (char*)d_ws;
    float4* pts4        = (float4*)ws;  ws += (size_t)n * sizeof(float4);
    float*  pbvT        = (float*)ws;   ws += (size_t)m * 64 * sizeof(float);
    int*    segbase     = (int*)ws;     ws += (size_t)NSEG * sizeof(int);
    int*    sorted_orig = (int*)ws;     ws += (size_t)m * sizeof(int);

    k1_mfma_scatter<<<NCH + MFMAB, 256, 0, stream>>>(points, dpts, sptids,
                                                     pts4, pbvT, segbase, sorted_orig,
                                                     (float*)d_out, n, m, NCH);
    k2_seg_pick<<<NSEG, 512, 0, stream>>>(pts4, dpts, scores, pbvT,
                                          segbase, sorted_orig, (float*)d_out, n, m);
}

// Round 16
// 49.105 us; speedup vs baseline: 1.9227x; 1.1587x over previous
//
#include <hip/hip_runtime.h>
#include <cfloat>
#include <cstdint>

#define NSEG 512
#define C 21
#define PPB 512                   // points per chunk
#define EPS_PICK 1e-3f            // >= 2*deltaM (f16-split emu err ~2e-5) and >= deltaM+delta32

typedef _Float16 half8 __attribute__((ext_vector_type(8)));   // 8 f16 (MFMA A/B frag)
typedef float f32x16 __attribute__((ext_vector_type(16)));    // 32x32 MFMA acc

// ===================== K1: scatter + self-staged f16 MFMA (R15-validated, verbatim) =====================
// bid 0..63   : scatter chunk sb — self-contained stable counting sort of d_points
//               (out positions + sorted_orig); sb==0 also writes segbase[].
// bid 64..2111: mfma block b2=bid-64, qb=b2&31, pc=b2>>5 — self-stage chunk pc
//               (512 pts) as f16 2-level-split slots in LDS (frag-major, 16 KB) and
//               B-frags for 128 queries/wave from raw dpts; 16 tt x 4 MFMA
//               (32x32x16 f16); fold 16 accs + xor(32) -> per-chunk min pbvT[q][pc].
//               qb==0 blocks also write pts4.
// K-slot layout (K=16, 11 used), per coord c (a=-2*p_c, b=q_c; ah/al = f16 Dekker):
//   slots 3c..3c+2: A=[ah,ah,al]  B=[bh,bl,bh]
//   slots 9,10:     A=[s0,s1] (|p|^2 2-level)  B=[1,1];  slots 11..15: 0
__global__ __launch_bounds__(256, 4)
void k1_mfma_scatter(const float* __restrict__ pts, const float* __restrict__ dpts,
                     const int* __restrict__ sptids,
                     float4* __restrict__ pts4, float* __restrict__ pbvT,
                     int* __restrict__ segbase, int* __restrict__ sorted_orig,
                     float* __restrict__ out, int n, int m, int NCH)
{
    __shared__ half8 lbuf[1024];                  // 16 KB (A-chunk / scatter scratch)
    const int bid = blockIdx.x, t = threadIdx.x;

    if (bid < NCH) {
        // ---- scatter chunk sb: stable counting sort (R12-R15 validated) ----
        int sb = bid;
        int* Hb   = (int*)lbuf;                   // [512] counts with idx < sb*256
        int* Ht   = Hb + NSEG;                    // [512] total counts
        int* pair = Ht + NSEG;                    // [256] pair sums for scan
        int* segs = pair + 256;                   // [256] this chunk's sptids
        Hb[t] = 0; Hb[t + 256] = 0; Ht[t] = 0; Ht[t + 256] = 0;
        __syncthreads();
        int before = sb * 256;
        for (int idx = t; idx < m; idx += 256) {  // integer LDS atomics -> deterministic
            int s = sptids[idx];
            atomicAdd(&Ht[s], 1);
            if (idx < before) atomicAdd(&Hb[s], 1);
        }
        __syncthreads();
        int e0 = Ht[2 * t], e1 = Ht[2 * t + 1];
        int v = e0 + e1;
        pair[t] = v;
        __syncthreads();
        for (int off = 1; off < 256; off <<= 1) { // inclusive scan of pair sums
            int add = (t >= off) ? pair[t - off] : 0;
            __syncthreads();
            v += add; pair[t] = v;
            __syncthreads();
        }
        int prev = (t > 0) ? pair[t - 1] : 0;
        int b0 = prev, b1 = prev + e0;            // exclusive bases of bins 2t, 2t+1
        if (sb == 0) { segbase[2 * t] = b0; segbase[2 * t + 1] = b1; }
        int hb0 = Hb[2 * t], hb1 = Hb[2 * t + 1];
        __syncthreads();                          // all Hb reads done before overwrite
        Hb[2 * t] = b0 + hb0;
        Hb[2 * t + 1] = b1 + hb1;
        int i = sb * 256 + t;
        segs[t] = (i < m) ? sptids[i] : -1;
        __syncthreads();
        if (i < m) {
            int seg = segs[t];
            int rank = 0;
            for (int j = 0; j < t; j++) rank += (segs[j] == seg) ? 1 : 0;  // stable
            int pos = Hb[seg] + rank;
            out[pos * 3 + 0] = dpts[i * 3 + 0];
            out[pos * 3 + 1] = dpts[i * 3 + 1];
            out[pos * 3 + 2] = dpts[i * 3 + 2];
            sorted_orig[pos] = i;
        }
        return;
    }

    // ---- MFMA block ----
    const int b2 = bid - NCH;
    const int qb = b2 & 31, pc = b2 >> 5;
    const int wave = t >> 6, lane = t & 63;
    const int g = lane >> 5, col = lane & 31;

    // B-frags: 4 query-tiles/wave, each lane builds its (g, col) entry from raw dpts
    half8 bq[4];
#pragma unroll
    for (int k = 0; k < 4; k++) {
        int q = (qb * 16 + wave * 4 + k) * 32 + col;
        float b0 = dpts[q * 3 + 0], b1 = dpts[q * 3 + 1], b2c = dpts[q * 3 + 2];
        _Float16 bh0 = (_Float16)b0; _Float16 bl0 = (_Float16)(b0 - (float)bh0);
        _Float16 bh1 = (_Float16)b1; _Float16 bl1 = (_Float16)(b1 - (float)bh1);
        _Float16 bh2 = (_Float16)b2c; _Float16 bl2 = (_Float16)(b2c - (float)bh2);
        const _Float16 one = (_Float16)1.f, zz = (_Float16)0.f;
        half8 g0 = {bh0, bl0, bh0, bh1, bl1, bh1, bh2, bl2};   // slots 0..7
        half8 g1 = {bh2, one, one, zz, zz, zz, zz, zz};        // slots 8..15
        bq[k] = g ? g1 : g0;
    }

    // A-chunk self-stage: thread stages points j=t and j+256 of chunk pc
#pragma unroll
    for (int half = 0; half < 2; half++) {
        int j = half * 256 + t;
        int i = pc * PPB + j;
        float x = pts[i * 3 + 0], y = pts[i * 3 + 1], z = pts[i * 3 + 2];
        if (qb == 0)                              // pts4 written exactly once per point
            pts4[i] = make_float4(x, y, z, fmaf(x, x, fmaf(y, y, z * z)));
        float a0 = -2.f * x, a1 = -2.f * y, a2 = -2.f * z;      // exact in f32
        _Float16 ah0 = (_Float16)a0; _Float16 al0 = (_Float16)(a0 - (float)ah0);
        _Float16 ah1 = (_Float16)a1; _Float16 al1 = (_Float16)(a1 - (float)ah1);
        _Float16 ah2 = (_Float16)a2; _Float16 al2 = (_Float16)(a2 - (float)ah2);
        double ps = (double)x * x + (double)y * y + (double)z * z;
        _Float16 s0 = (_Float16)(float)ps;
        double r1 = ps - (double)(float)s0;
        _Float16 s1 = (_Float16)(float)r1;
        half8 g0 = {ah0, ah0, al0, ah1, ah1, al1, ah2, ah2};    // slots 0..7
        half8 g1 = {al2, s0, s1, (_Float16)0.f, (_Float16)0.f,
                    (_Float16)0.f, (_Float16)0.f, (_Float16)0.f};
        int base = (j >> 5) * 64 + (j & 31) * 2;
        lbuf[base + 0] = g0;
        lbuf[base + 1] = g1;
    }
    __syncthreads();

    // ---- MFMA loop ----
    float run0 = FLT_MAX, run1 = FLT_MAX, run2 = FLT_MAX, run3 = FLT_MAX;
    const f32x16 zero = {0.f,0.f,0.f,0.f,0.f,0.f,0.f,0.f,0.f,0.f,0.f,0.f,0.f,0.f,0.f,0.f};
    const int aoff = col * 2 + g;

#pragma unroll 4
    for (int tt = 0; tt < 16; tt++) {
        half8 a = lbuf[tt * 64 + aoff];           // 16B b128, conflict-free
        f32x16 c0 = __builtin_amdgcn_mfma_f32_32x32x16_f16(a, bq[0], zero, 0, 0, 0);
        f32x16 c1 = __builtin_amdgcn_mfma_f32_32x32x16_f16(a, bq[1], zero, 0, 0, 0);
        f32x16 c2 = __builtin_amdgcn_mfma_f32_32x32x16_f16(a, bq[2], zero, 0, 0, 0);
        f32x16 c3 = __builtin_amdgcn_mfma_f32_32x32x16_f16(a, bq[3], zero, 0, 0, 0);
#define FOLD(cc, rr)  { \
        float v = fminf(fminf(cc[0], cc[1]), cc[2]);   \
        v = fminf(fminf(v, cc[3]), cc[4]);             \
        v = fminf(fminf(v, cc[5]), cc[6]);             \
        v = fminf(fminf(v, cc[7]), cc[8]);             \
        v = fminf(fminf(v, cc[9]), cc[10]);            \
        v = fminf(fminf(v, cc[11]), cc[12]);           \
        v = fminf(fminf(v, cc[13]), cc[14]);           \
        rr = fminf(fminf(v, cc[15]), rr); }
        FOLD(c0, run0) FOLD(c1, run1) FOLD(c2, run2) FOLD(c3, run3)
#undef FOLD
    }

    {   // merge the two 32-lane halves (rows), write 32 query chunk-mins per tile
        int qbase = (qb * 512 + wave * 128) * 64;
        float v0 = fminf(run0, __shfl_xor(run0, 32, 64));
        float v1 = fminf(run1, __shfl_xor(run1, 32, 64));
        float v2 = fminf(run2, __shfl_xor(run2, 32, 64));
        float v3 = fminf(run3, __shfl_xor(run3, 32, 64));
        if (lane < 32) {
            pbvT[(size_t)qbase + (0 * 32 + lane) * 64 + pc] = v0;
            pbvT[(size_t)qbase + (1 * 32 + lane) * 64 + pc] = v1;
            pbvT[(size_t)qbase + (2 * 32 + lane) * 64 + pc] = v2;
            pbvT[(size_t)qbase + (3 * 32 + lane) * 64 + pc] = v3;
        }
    }
}

// ===================== K2: seg_pick_final (1024 threads = 16 waves) =====================
// One block per segment, 16 waves. Each wave resolves the NN for its members
// (j = base+wave, step 16): lane pc reads pbvT[q][pc], butterfly min -> g1,
// ballot(v<=g1+EPS) -> chunk mask, f32-filtered exact f64 resolve with
// lowest-index tie-break (== full f64 argmin, math verbatim R12-R15). Lane c<21
// accumulates scores[nn][c] in f64 in fixed (j, wave) order -> deterministic.
// Block reduce (fixed wave order) -> argmax (strict >, first max wins) ->
// labels written to original positions. argmax(sum) == argmax(mean).
__global__ __launch_bounds__(1024)
void k2_seg_pick(const float4* __restrict__ pts4, const float* __restrict__ dpts,
                 const float* __restrict__ scores, const float* __restrict__ pbvT,
                 const int* __restrict__ segbase, const int* __restrict__ sorted_orig,
                 float* __restrict__ out, int n, int m)
{
    __shared__ double wsum[16][C];
    __shared__ double total[C];
    __shared__ float lab;
    const int t = threadIdx.x, wave = t >> 6, lane = t & 63;
    const int s = blockIdx.x;
    const int base = segbase[s];
    const int end  = (s == NSEG - 1) ? m : segbase[s + 1];

    double acc = 0.0;                             // channel `lane` partial (lanes 0..20)
    for (int j = base + wave; j < end; j += 16) {
        int q = sorted_orig[j];
        float myv = pbvT[(size_t)q * 64 + lane];  // chunk `lane` min (coalesced 256B)
        float g1 = myv;
#pragma unroll
        for (int off = 1; off < 64; off <<= 1) g1 = fminf(g1, __shfl_xor(g1, off, 64));
        float thr = g1 + EPS_PICK;
        unsigned long long msk = __ballot(myv <= thr);   // bit pc == chunk qualifies

        float fx = dpts[q * 3 + 0], fy = dpts[q * 3 + 1], fz = dpts[q * 3 + 2];
        float fm2x = -2.f * fx, fm2y = -2.f * fy, fm2z = -2.f * fz;
        double m2x = -2.0 * (double)fx, m2y = -2.0 * (double)fy, m2z = -2.0 * (double)fz;
        double best = 1e308; int bi = 0x7fffffff;
        while (msk) {
            int pc = __builtin_ctzll(msk); msk &= msk - 1;
            int pbase = pc * PPB + lane;
#pragma unroll
            for (int r2 = 0; r2 < PPB / 64; r2++) {
                int i = pbase + r2 * 64;
                if (i < n) {
                    float4 p = pts4[i];
                    float v = fmaf(p.x, fm2x, fmaf(p.y, fm2y, fmaf(p.z, fm2z, p.w)));
                    if (v <= thr) {
                        double ps = (double)p.x * p.x + (double)p.y * p.y + (double)p.z * p.z;
                        double dv = fma((double)p.x, m2x, fma((double)p.y, m2y,
                                    fma((double)p.z, m2z, ps)));
                        if (dv < best || (dv == best && i < bi)) { best = dv; bi = i; }
                    }
                }
            }
        }
#pragma unroll
        for (int off = 32; off; off >>= 1) {
            double ov = __shfl_down(best, off, 64);
            int oi = __shfl_down(bi, off, 64);
            if (ov < best || (ov == best && oi < bi)) { best = ov; bi = oi; }
        }
        int bi0 = __shfl(bi, 0, 64);              // broadcast winner index
        if (lane < C)
            acc += (double)scores[(size_t)bi0 * C + lane];
    }
    if (lane < C) wsum[wave][lane] = acc;         // all 16 waves write (0.0 if no members)
    __syncthreads();
    if (t < C) {
        double tv = 0.0;
#pragma unroll
        for (int w = 0; w < 16; w++) tv += wsum[w][t];   // fixed wave order
        total[t] = tv;
    }
    __syncthreads();
    if (t == 0) {
        double bv = total[0]; int best = 0;
        for (int c = 1; c < C; c++)
            if (total[c] > bv) { bv = total[c]; best = c; }  // strict >: first max wins
        lab = (float)best;
    }
    __syncthreads();
    float fb = lab;
    for (int j = base + t; j < end; j += 1024)    // labels in ORIGINAL order
        out[(size_t)m * 3 + sorted_orig[j]] = fb;
}

extern "C" void kernel_launch(void* const* d_in, const int* in_sizes, int n_in,
                              void* d_out, int out_size, void* d_ws, size_t ws_size,
                              hipStream_t stream) {
    const float* points = (const float*)d_in[0];
    const float* scores = (const float*)d_in[1];
    const float* dpts   = (const float*)d_in[2];
    const int*   sptids = (const int*)d_in[3];

    int n = in_sizes[0] / 3;          // 32768
    int m = in_sizes[2] / 3;          // 16384
    int NCH   = (m + 255) / 256;      // 64 scatter chunks
    int QB    = (m + 511) / 512;      // 32 query blocks
    int PCg   = (n + 511) / 512;      // 64 point chunks
    int MFMAB = QB * PCg;             // 2048 mfma blocks

    char* ws = (char*)d_ws;
    float4* pts4        = (float4*)ws;  ws += (size_t)n * sizeof(float4);
    float*  pbvT        = (float*)ws;   ws += (size_t)m * 64 * sizeof(float);
    int*    segbase     = (int*)ws;     ws += (size_t)NSEG * sizeof(int);
    int*    sorted_orig = (int*)ws;     ws += (size_t)m * sizeof(int);

    k1_mfma_scatter<<<NCH + MFMAB, 256, 0, stream>>>(points, dpts, sptids,
                                                     pts4, pbvT, segbase, sorted_orig,
                                                     (float*)d_out, n, m, NCH);
    k2_seg_pick<<<NSEG, 1024, 0, stream>>>(pts4, dpts, scores, pbvT,
                                           segbase, sorted_orig, (float*)d_out, n, m);
}

// Round 17
// 47.084 us; speedup vs baseline: 2.0053x; 1.0429x over previous
//
#include <hip/hip_runtime.h>
#include <cfloat>
#include <cstdint>

#define NSEG 512
#define C 21
#define PPB 512                   // points per chunk
#define EPS_PICK 1e-3f            // >= 2*deltaM (f16-split emu err ~2e-5) and >= deltaM+delta32
#define SLACK 1.5e-4f             // covers 16-ULP(|v|<64) aux quantization of L (6.1e-5)

typedef _Float16 half8 __attribute__((ext_vector_type(8)));   // 8 f16 (MFMA A/B frag)
typedef float f32x16 __attribute__((ext_vector_type(16)));    // 32x32 MFMA acc

// ===================== K1: scatter + self-staged f16 MFMA =====================
// bid 0..63   : scatter chunk sb — stable counting sort of d_points (R12-R16 validated);
//               sb==0 also writes segbase[].
// bid 64..2111: mfma block — self-stage chunk pc as f16 2-level-split slots (16 KB LDS),
//               B-frags for 128 queries/wave; 16 tt x 4 MFMA (32x32x16 f16).
//               NEW: per-query track (run1, run2-of-tile-mins, winning tile T*);
//               cross-half merge gives chunk min r1c and a lower bound L on all
//               non-T* tile mins -> pbvT[q][pc]=r1c, auxT[q][pc]=(bits(L)&~0xF)|T*.
// K-slot layout (K=16, 11 used), per coord c (a=-2*p_c, b=q_c; ah/al = f16 Dekker):
//   slots 3c..3c+2: A=[ah,ah,al]  B=[bh,bl,bh]
//   slots 9,10:     A=[s0,s1] (|p|^2 2-level)  B=[1,1];  slots 11..15: 0
__global__ __launch_bounds__(256, 4)
void k1_mfma_scatter(const float* __restrict__ pts, const float* __restrict__ dpts,
                     const int* __restrict__ sptids,
                     float4* __restrict__ pts4, float* __restrict__ pbvT,
                     unsigned* __restrict__ auxT,
                     int* __restrict__ segbase, int* __restrict__ sorted_orig,
                     float* __restrict__ out, int n, int m, int NCH)
{
    __shared__ half8 lbuf[1024];                  // 16 KB (A-chunk / scatter scratch)
    const int bid = blockIdx.x, t = threadIdx.x;

    if (bid < NCH) {
        // ---- scatter chunk sb: stable counting sort (R12-R16 validated, verbatim) ----
        int sb = bid;
        int* Hb   = (int*)lbuf;
        int* Ht   = Hb + NSEG;
        int* pair = Ht + NSEG;
        int* segs = pair + 256;
        Hb[t] = 0; Hb[t + 256] = 0; Ht[t] = 0; Ht[t + 256] = 0;
        __syncthreads();
        int before = sb * 256;
        for (int idx = t; idx < m; idx += 256) {
            int s = sptids[idx];
            atomicAdd(&Ht[s], 1);
            if (idx < before) atomicAdd(&Hb[s], 1);
        }
        __syncthreads();
        int e0 = Ht[2 * t], e1 = Ht[2 * t + 1];
        int v = e0 + e1;
        pair[t] = v;
        __syncthreads();
        for (int off = 1; off < 256; off <<= 1) {
            int add = (t >= off) ? pair[t - off] : 0;
            __syncthreads();
            v += add; pair[t] = v;
            __syncthreads();
        }
        int prev = (t > 0) ? pair[t - 1] : 0;
        int b0 = prev, b1 = prev + e0;
        if (sb == 0) { segbase[2 * t] = b0; segbase[2 * t + 1] = b1; }
        int hb0 = Hb[2 * t], hb1 = Hb[2 * t + 1];
        __syncthreads();
        Hb[2 * t] = b0 + hb0;
        Hb[2 * t + 1] = b1 + hb1;
        int i = sb * 256 + t;
        segs[t] = (i < m) ? sptids[i] : -1;
        __syncthreads();
        if (i < m) {
            int seg = segs[t];
            int rank = 0;
            for (int j = 0; j < t; j++) rank += (segs[j] == seg) ? 1 : 0;
            int pos = Hb[seg] + rank;
            out[pos * 3 + 0] = dpts[i * 3 + 0];
            out[pos * 3 + 1] = dpts[i * 3 + 1];
            out[pos * 3 + 2] = dpts[i * 3 + 2];
            sorted_orig[pos] = i;
        }
        return;
    }

    // ---- MFMA block ----
    const int b2 = bid - NCH;
    const int qb = b2 & 31, pc = b2 >> 5;
    const int wave = t >> 6, lane = t & 63;
    const int g = lane >> 5, col = lane & 31;

    half8 bq[4];                                  // B-frags from raw dpts
#pragma unroll
    for (int k = 0; k < 4; k++) {
        int q = (qb * 16 + wave * 4 + k) * 32 + col;
        float b0 = dpts[q * 3 + 0], b1 = dpts[q * 3 + 1], b2c = dpts[q * 3 + 2];
        _Float16 bh0 = (_Float16)b0; _Float16 bl0 = (_Float16)(b0 - (float)bh0);
        _Float16 bh1 = (_Float16)b1; _Float16 bl1 = (_Float16)(b1 - (float)bh1);
        _Float16 bh2 = (_Float16)b2c; _Float16 bl2 = (_Float16)(b2c - (float)bh2);
        const _Float16 one = (_Float16)1.f, zz = (_Float16)0.f;
        half8 g0 = {bh0, bl0, bh0, bh1, bl1, bh1, bh2, bl2};
        half8 g1 = {bh2, one, one, zz, zz, zz, zz, zz};
        bq[k] = g ? g1 : g0;
    }

#pragma unroll
    for (int half = 0; half < 2; half++) {        // stage points t, t+256 of chunk pc
        int j = half * 256 + t;
        int i = pc * PPB + j;
        float x = pts[i * 3 + 0], y = pts[i * 3 + 1], z = pts[i * 3 + 2];
        if (qb == 0)
            pts4[i] = make_float4(x, y, z, fmaf(x, x, fmaf(y, y, z * z)));
        float a0 = -2.f * x, a1 = -2.f * y, a2 = -2.f * z;
        _Float16 ah0 = (_Float16)a0; _Float16 al0 = (_Float16)(a0 - (float)ah0);
        _Float16 ah1 = (_Float16)a1; _Float16 al1 = (_Float16)(a1 - (float)ah1);
        _Float16 ah2 = (_Float16)a2; _Float16 al2 = (_Float16)(a2 - (float)ah2);
        double ps = (double)x * x + (double)y * y + (double)z * z;
        _Float16 s0 = (_Float16)(float)ps;
        double r1 = ps - (double)(float)s0;
        _Float16 s1 = (_Float16)(float)r1;
        half8 g0 = {ah0, ah0, al0, ah1, ah1, al1, ah2, ah2};
        half8 g1 = {al2, s0, s1, (_Float16)0.f, (_Float16)0.f,
                    (_Float16)0.f, (_Float16)0.f, (_Float16)0.f};
        int base = (j >> 5) * 64 + (j & 31) * 2;
        lbuf[base + 0] = g0;
        lbuf[base + 1] = g1;
    }
    __syncthreads();

    // ---- MFMA loop with per-tile (run1, run2, tti) tracking ----
    float run1[4], run2[4];
    int ttix[4];
#pragma unroll
    for (int k = 0; k < 4; k++) { run1[k] = FLT_MAX; run2[k] = FLT_MAX; ttix[k] = 0; }
    const f32x16 zero = {0.f,0.f,0.f,0.f,0.f,0.f,0.f,0.f,0.f,0.f,0.f,0.f,0.f,0.f,0.f,0.f};
    const int aoff = col * 2 + g;

#pragma unroll 4
    for (int tt = 0; tt < 16; tt++) {
        half8 a = lbuf[tt * 64 + aoff];           // 16B b128, conflict-free
        f32x16 c0 = __builtin_amdgcn_mfma_f32_32x32x16_f16(a, bq[0], zero, 0, 0, 0);
        f32x16 c1 = __builtin_amdgcn_mfma_f32_32x32x16_f16(a, bq[1], zero, 0, 0, 0);
        f32x16 c2 = __builtin_amdgcn_mfma_f32_32x32x16_f16(a, bq[2], zero, 0, 0, 0);
        f32x16 c3 = __builtin_amdgcn_mfma_f32_32x32x16_f16(a, bq[3], zero, 0, 0, 0);
#define FOLD(cc, kk)  { \
        float v = fminf(fminf(cc[0], cc[1]), cc[2]);   \
        v = fminf(fminf(v, cc[3]), cc[4]);             \
        v = fminf(fminf(v, cc[5]), cc[6]);             \
        v = fminf(fminf(v, cc[7]), cc[8]);             \
        v = fminf(fminf(v, cc[9]), cc[10]);            \
        v = fminf(fminf(v, cc[11]), cc[12]);           \
        v = fminf(fminf(v, cc[13]), cc[14]);           \
        v = fminf(v, cc[15]);                          \
        float nr2 = fminf(run2[kk], fmaxf(v, run1[kk])); \
        if (v < run1[kk]) { ttix[kk] = tt; run1[kk] = v; } \
        run2[kk] = nr2; }
        FOLD(c0, 0) FOLD(c1, 1) FOLD(c2, 2) FOLD(c3, 3)
#undef FOLD
    }

    // ---- cross-half merge: chunk min r1c, winner tile T*, lower bound L on other tiles ----
#pragma unroll
    for (int k = 0; k < 4; k++) {
        float o1 = __shfl_xor(run1[k], 32, 64);
        float o2 = __shfl_xor(run2[k], 32, 64);
        int   ot = __shfl_xor(ttix[k], 32, 64);
        // symmetric lo/hi assignment so both lanes agree on T*
        float lo1 = (lane < 32) ? run1[k] : o1;  int loT = (lane < 32) ? ttix[k] : ot;
        float lo2 = (lane < 32) ? run2[k] : o2;
        float hi1 = (lane < 32) ? o1 : run1[k];  int hiT = (lane < 32) ? ot : ttix[k];
        float hi2 = (lane < 32) ? o2 : run2[k];
        float r1c = fminf(lo1, hi1);
        int Tstar = (lo1 <= hi1) ? loT : hiT;
        // for any tile T != T*: vt_half(T) >= (half.tti!=T* ? half.run1 : half.run2)
        float cl = (loT != Tstar) ? lo1 : lo2;
        float ch = (hiT != Tstar) ? hi1 : hi2;
        float L = fminf(cl, ch);
        if (lane < 32) {
            size_t qi = (size_t)(qb * 512 + wave * 128 + k * 32 + lane) * 64 + pc;
            pbvT[qi] = r1c;
            auxT[qi] = (__float_as_uint(L) & ~0xFu) | (unsigned)Tstar;
        }
    }
}

// ===================== K2: seg_pick_final (16 waves, tile-narrowed rescan) =====================
// One block per segment, 16 waves. Per member q: pbvT read -> butterfly min -> g1;
// ballot(v<=g1+EPS) -> chunk mask. Per qualifying chunk: read auxT; if the
// non-winner-tile lower bound L > thr+SLACK, only tile T* can hold candidates ->
// scan 32 points; else full 512-point scan (R12-R16 validated path). Survivors of
// the f32 filter get exact f64 eval; lowest-index tie-break == full f64 argmin.
// Lane c<21 accumulates scores[nn][c] in f64, fixed (j,wave) order -> deterministic;
// block argmax (strict >) -> labels to original positions.
__global__ __launch_bounds__(1024)
void k2_seg_pick(const float4* __restrict__ pts4, const float* __restrict__ dpts,
                 const float* __restrict__ scores, const float* __restrict__ pbvT,
                 const unsigned* __restrict__ auxT,
                 const int* __restrict__ segbase, const int* __restrict__ sorted_orig,
                 float* __restrict__ out, int n, int m)
{
    __shared__ double wsum[16][C];
    __shared__ double total[C];
    __shared__ float lab;
    const int t = threadIdx.x, wave = t >> 6, lane = t & 63;
    const int s = blockIdx.x;
    const int base = segbase[s];
    const int end  = (s == NSEG - 1) ? m : segbase[s + 1];

    double acc = 0.0;                             // channel `lane` partial (lanes 0..20)
    for (int j = base + wave; j < end; j += 16) {
        int q = sorted_orig[j];
        float myv = pbvT[(size_t)q * 64 + lane];
        float g1 = myv;
#pragma unroll
        for (int off = 1; off < 64; off <<= 1) g1 = fminf(g1, __shfl_xor(g1, off, 64));
        float thr = g1 + EPS_PICK;
        unsigned long long msk = __ballot(myv <= thr);

        float fx = dpts[q * 3 + 0], fy = dpts[q * 3 + 1], fz = dpts[q * 3 + 2];
        float fm2x = -2.f * fx, fm2y = -2.f * fy, fm2z = -2.f * fz;
        double m2x = -2.0 * (double)fx, m2y = -2.0 * (double)fy, m2z = -2.0 * (double)fz;
        double best = 1e308; int bi = 0x7fffffff;
        while (msk) {
            int pc = __builtin_ctzll(msk); msk &= msk - 1;
            unsigned au = auxT[(size_t)q * 64 + pc];     // lane-uniform -> broadcast
            float L = __uint_as_float(au & ~0xFu);
            int Ts = (int)(au & 0xFu);
            if (L > thr + SLACK) {
                // only tile T* can contain candidates: scan 32 points (lanes 0..31)
                if (lane < 32) {
                    int i = pc * PPB + Ts * 32 + lane;
                    if (i < n) {
                        float4 p = pts4[i];
                        float v = fmaf(p.x, fm2x, fmaf(p.y, fm2y, fmaf(p.z, fm2z, p.w)));
                        if (v <= thr) {
                            double ps = (double)p.x * p.x + (double)p.y * p.y + (double)p.z * p.z;
                            double dv = fma((double)p.x, m2x, fma((double)p.y, m2y,
                                        fma((double)p.z, m2z, ps)));
                            if (dv < best || (dv == best && i < bi)) { best = dv; bi = i; }
                        }
                    }
                }
            } else {
                // fallback: full 512-point chunk scan (validated path)
                int pbase = pc * PPB + lane;
#pragma unroll
                for (int r2 = 0; r2 < PPB / 64; r2++) {
                    int i = pbase + r2 * 64;
                    if (i < n) {
                        float4 p = pts4[i];
                        float v = fmaf(p.x, fm2x, fmaf(p.y, fm2y, fmaf(p.z, fm2z, p.w)));
                        if (v <= thr) {
                            double ps = (double)p.x * p.x + (double)p.y * p.y + (double)p.z * p.z;
                            double dv = fma((double)p.x, m2x, fma((double)p.y, m2y,
                                        fma((double)p.z, m2z, ps)));
                            if (dv < best || (dv == best && i < bi)) { best = dv; bi = i; }
                        }
                    }
                }
            }
        }
#pragma unroll
        for (int off = 32; off; off >>= 1) {
            double ov = __shfl_down(best, off, 64);
            int oi = __shfl_down(bi, off, 64);
            if (ov < best || (ov == best && oi < bi)) { best = ov; bi = oi; }
        }
        int bi0 = __shfl(bi, 0, 64);
        if (lane < C)
            acc += (double)scores[(size_t)bi0 * C + lane];
    }
    if (lane < C) wsum[wave][lane] = acc;
    __syncthreads();
    if (t < C) {
        double tv = 0.0;
#pragma unroll
        for (int w = 0; w < 16; w++) tv += wsum[w][t];   // fixed wave order
        total[t] = tv;
    }
    __syncthreads();
    if (t == 0) {
        double bv = total[0]; int best = 0;
        for (int c = 1; c < C; c++)
            if (total[c] > bv) { bv = total[c]; best = c; }  // strict >: first max wins
        lab = (float)best;
    }
    __syncthreads();
    float fb = lab;
    for (int j = base + t; j < end; j += 1024)    // labels in ORIGINAL order
        out[(size_t)m * 3 + sorted_orig[j]] = fb;
}

extern "C" void kernel_launch(void* const* d_in, const int* in_sizes, int n_in,
                              void* d_out, int out_size, void* d_ws, size_t ws_size,
                              hipStream_t stream) {
    const float* points = (const float*)d_in[0];
    const float* scores = (const float*)d_in[1];
    const float* dpts   = (const float*)d_in[2];
    const int*   sptids = (const int*)d_in[3];

    int n = in_sizes[0] / 3;          // 32768
    int m = in_sizes[2] / 3;          // 16384
    int NCH   = (m + 255) / 256;      // 64 scatter chunks
    int QB    = (m + 511) / 512;      // 32 query blocks
    int PCg   = (n + 511) / 512;      // 64 point chunks
    int MFMAB = QB * PCg;             // 2048 mfma blocks

    char* ws = (char*)d_ws;
    float4*   pts4        = (float4*)ws;    ws += (size_t)n * sizeof(float4);
    float*    pbvT        = (float*)ws;     ws += (size_t)m * 64 * sizeof(float);
    unsigned* auxT        = (unsigned*)ws;  ws += (size_t)m * 64 * sizeof(unsigned);
    int*      segbase     = (int*)ws;       ws += (size_t)NSEG * sizeof(int);
    int*      sorted_orig = (int*)ws;       ws += (size_t)m * sizeof(int);

    k1_mfma_scatter<<<NCH + MFMAB, 256, 0, stream>>>(points, dpts, sptids,
                                                     pts4, pbvT, auxT, segbase,
                                                     sorted_orig, (float*)d_out, n, m, NCH);
    k2_seg_pick<<<NSEG, 1024, 0, stream>>>(pts4, dpts, scores, pbvT, auxT,
                                           segbase, sorted_orig, (float*)d_out, n, m);
}